// Round 1
// baseline (301.108 us; speedup 1.0000x reference)
//
#include <hip/hip_runtime.h>
#include <hip/hip_bf16.h>
#include <math.h>

// Shapes (fixed by the reference problem)
#define BB 2
#define TT 2048
#define CC 512
#define HH 8
#define DD 64
#define KK 4
#define C3 1536
#define MROWS (BB*TT)          // 4096

// ---------------------------------------------------------------------------
// Kernel 1/5: generic fp32 tiled GEMM with bias: C[M,N] = A[M,K]@B[K,N]+bias
// 64x64 tile, BK=16, 256 threads, 4x4 per thread.
// ---------------------------------------------------------------------------
__global__ __launch_bounds__(256) void gemm_bias_kernel(
    const float* __restrict__ A, const float* __restrict__ B,
    const float* __restrict__ bias, float* __restrict__ C,
    int M, int N, int K) {
  __shared__ float As[16][65];
  __shared__ float Bs[16][64];
  const int tid = threadIdx.x;
  const int tx = tid & 15;
  const int ty = tid >> 4;
  const int rowBase = blockIdx.y * 64;
  const int colBase = blockIdx.x * 64;
  float acc[4][4] = {};

  for (int k0 = 0; k0 < K; k0 += 16) {
#pragma unroll
    for (int i = 0; i < 4; ++i) {
      int idx = tid + i * 256;      // 0..1023
      int m  = idx >> 4;            // 0..63
      int kk = idx & 15;
      As[kk][m] = A[(size_t)(rowBase + m) * K + k0 + kk];
    }
#pragma unroll
    for (int i = 0; i < 4; ++i) {
      int idx = tid + i * 256;
      int kk = idx >> 6;            // 0..15
      int n  = idx & 63;
      Bs[kk][n] = B[(size_t)(k0 + kk) * N + colBase + n];
    }
    __syncthreads();
#pragma unroll
    for (int kk = 0; kk < 16; ++kk) {
      float a[4], b[4];
#pragma unroll
      for (int i = 0; i < 4; ++i) a[i] = As[kk][ty * 4 + i];
#pragma unroll
      for (int j = 0; j < 4; ++j) b[j] = Bs[kk][tx * 4 + j];
#pragma unroll
      for (int i = 0; i < 4; ++i)
#pragma unroll
        for (int j = 0; j < 4; ++j) acc[i][j] += a[i] * b[j];
    }
    __syncthreads();
  }
#pragma unroll
  for (int i = 0; i < 4; ++i) {
    int r = rowBase + ty * 4 + i;
#pragma unroll
    for (int j = 0; j < 4; ++j) {
      int c = colBase + tx * 4 + j;
      C[(size_t)r * N + c] = acc[i][j] + bias[c];
    }
  }
}

// ---------------------------------------------------------------------------
// Kernel 2/5: exact top-4 per tau row (2048), tie-break = smaller index wins
// (matches jax.lax.top_k). One block (256 thr) per row; 4 argmax passes.
// ---------------------------------------------------------------------------
__global__ __launch_bounds__(256) void topk_kernel(
    const float* __restrict__ tau, int* __restrict__ idx_out) {
  __shared__ float vals[TT];
  __shared__ float rv[256];
  __shared__ int   ri[256];
  const int row = blockIdx.x;
  const float* rp = tau + (size_t)row * TT;
  const int tid = threadIdx.x;
#pragma unroll
  for (int i = 0; i < TT / 256; ++i) vals[tid + i * 256] = rp[tid + i * 256];
  __syncthreads();

  int chosen[KK];
  for (int r = 0; r < KK; ++r) {
    float bv = -1e30f;
    int bi = 1 << 20;
#pragma unroll
    for (int i = 0; i < TT / 256; ++i) {
      int s = tid + i * 256;
      float v = vals[s];
      if (v > bv || (v == bv && s < bi)) { bv = v; bi = s; }
    }
    rv[tid] = bv; ri[tid] = bi;
    __syncthreads();
    for (int off = 128; off > 0; off >>= 1) {
      if (tid < off) {
        float v2 = rv[tid + off]; int i2 = ri[tid + off];
        if (v2 > rv[tid] || (v2 == rv[tid] && i2 < ri[tid])) {
          rv[tid] = v2; ri[tid] = i2;
        }
      }
      __syncthreads();
    }
    int win = ri[0];
    chosen[r] = win;
    if (tid == 0) vals[win] = -1e30f;
    __syncthreads();
  }
  if (tid < KK) idx_out[row * KK + tid] = chosen[tid];
}

// ---------------------------------------------------------------------------
// Kernel 3/5: sparse attention at the 4 top-k keys.
// Block = one (b,t): 8 waves, wave h = head h, lane = d.
// Produces attn_out[b,t,h*64+d] and sig[b,t,j] = mean_h attn.
// ---------------------------------------------------------------------------
__global__ __launch_bounds__(512) void attn_kernel(
    const float* __restrict__ qkv, const float* __restrict__ tau,
    const int* __restrict__ idx_in, float* __restrict__ attn_out,
    float* __restrict__ sig_out) {
  const int row  = blockIdx.x;          // b*T + t
  const int b    = row >> 11;           // /T
  const int tid  = threadIdx.x;
  const int h    = tid >> 6;
  const int lane = tid & 63;

  __shared__ float sig[KK];
  __shared__ int   idx4[KK];
  __shared__ float tau4[KK];
  if (tid < KK) {
    int s = idx_in[row * KK + tid];
    idx4[tid] = s;
    tau4[tid] = tau[(size_t)row * TT + s];
    sig[tid] = 0.f;
  }
  __syncthreads();

  const size_t base_t = (size_t)row * C3;
  const float q = qkv[base_t + h * DD + lane];

  int   sidx[KK];
  float logit[KK];
#pragma unroll
  for (int j = 0; j < KK; ++j) {
    sidx[j] = idx4[j];
    size_t base_s = ((size_t)(b * TT + sidx[j])) * C3;
    float kv = qkv[base_s + CC + h * DD + lane];
    float p = q * kv;
#pragma unroll
    for (int off = 32; off > 0; off >>= 1) p += __shfl_xor(p, off, 64);
    logit[j] = p * 0.125f + 2.5f * logf(tau4[j] + 1e-8f);
  }

  float m = fmaxf(fmaxf(logit[0], logit[1]), fmaxf(logit[2], logit[3]));
  float p[KK], den = 0.f;
#pragma unroll
  for (int j = 0; j < KK; ++j) { p[j] = expf(logit[j] - m); den += p[j]; }
  float inv = 1.f / den;
#pragma unroll
  for (int j = 0; j < KK; ++j) p[j] *= inv;

  float o = 0.f;
#pragma unroll
  for (int j = 0; j < KK; ++j) {
    size_t base_s = ((size_t)(b * TT + sidx[j])) * C3;
    o += p[j] * qkv[base_s + 2 * CC + h * DD + lane];
  }
  attn_out[(size_t)row * CC + h * DD + lane] = o;

  if (lane == 0) {
#pragma unroll
    for (int j = 0; j < KK; ++j) atomicAdd(&sig[j], p[j]);
  }
  __syncthreads();
  if (tid < KK) sig_out[row * KK + tid] = sig[tid] * (1.0f / HH);
}

// ---------------------------------------------------------------------------
// Kernel 4/5: tau EMA update + row-normalize + clip.
// ---------------------------------------------------------------------------
__global__ __launch_bounds__(256) void tau_kernel(
    const float* __restrict__ tau, const int* __restrict__ idx_in,
    const float* __restrict__ sig_in, float* __restrict__ tau_out) {
  __shared__ float pre[TT];
  __shared__ float red[256];
  const int row = blockIdx.x;
  const int tid = threadIdx.x;

  int   i4[KK];
  float s3[KK];
#pragma unroll
  for (int j = 0; j < KK; ++j) {
    i4[j] = idx_in[row * KK + j];
    float s = sig_in[row * KK + j];
    s3[j] = s * s * s;
  }
  const float* rp = tau + (size_t)row * TT;
  const float keep = 1.0f - 0.085f;
  float local = 0.f;
#pragma unroll
  for (int i = 0; i < TT / 256; ++i) {
    int s = tid + i * 256;
    float v = keep * rp[s];
#pragma unroll
    for (int j = 0; j < KK; ++j)
      if (s == i4[j]) v += s3[j];
    pre[s] = v;
    local += v;
  }
  red[tid] = local;
  __syncthreads();
  for (int off = 128; off > 0; off >>= 1) {
    if (tid < off) red[tid] += red[tid + off];
    __syncthreads();
  }
  float inv = 1.f / (red[0] + 1e-8f);
#pragma unroll
  for (int i = 0; i < TT / 256; ++i) {
    int s = tid + i * 256;
    tau_out[(size_t)row * TT + s] = fminf(pre[s] * inv, 5.0f);
  }
}

// ---------------------------------------------------------------------------
extern "C" void kernel_launch(void* const* d_in, const int* in_sizes, int n_in,
                              void* d_out, int out_size, void* d_ws, size_t ws_size,
                              hipStream_t stream) {
  const float* x     = (const float*)d_in[0];   // [B,T,C]
  const float* tau   = (const float*)d_in[1];   // [B,T,T]
  const float* Wqkv  = (const float*)d_in[2];   // [C,3C]
  const float* bqkv  = (const float*)d_in[3];   // [3C]
  const float* Wproj = (const float*)d_in[4];   // [C,C]
  const float* bproj = (const float*)d_in[5];   // [C]

  float* out     = (float*)d_out;                       // [B,T,C]
  float* tau_new = out + (size_t)MROWS * CC;            // [B,T,T]

  float* qkv      = (float*)d_ws;                       // [4096,1536]
  float* attn_out = qkv + (size_t)MROWS * C3;           // [4096,512]
  int*   idx      = (int*)(attn_out + (size_t)MROWS * CC); // [4096,4]
  float* sig      = (float*)(idx + MROWS * KK);         // [4096,4]

  // 1) qkv = x @ Wqkv + bqkv
  dim3 g1(C3 / 64, MROWS / 64);
  gemm_bias_kernel<<<g1, 256, 0, stream>>>(x, Wqkv, bqkv, qkv, MROWS, C3, CC);

  // 2) top-4 indices of each tau row
  topk_kernel<<<MROWS, 256, 0, stream>>>(tau, idx);

  // 3) sparse attention + signal
  attn_kernel<<<MROWS, 512, 0, stream>>>(qkv, tau, idx, attn_out, sig);

  // 4) tau update
  tau_kernel<<<MROWS, 256, 0, stream>>>(tau, idx, sig, tau_new);

  // 5) out = attn_out @ Wproj + bproj
  dim3 g2(CC / 64, MROWS / 64);
  gemm_bias_kernel<<<g2, 256, 0, stream>>>(attn_out, Wproj, bproj, out, MROWS, CC, CC);
}

// Round 2
// 174.188 us; speedup vs baseline: 1.7286x; 1.7286x over previous
//
#include <hip/hip_runtime.h>
#include <hip/hip_bf16.h>
#include <math.h>

// Shapes (fixed by the reference problem)
#define BB 2
#define TT 2048
#define CC 512
#define HH 8
#define DD 64
#define KK 4
#define C3 1536
#define MROWS (BB*TT)          // 4096

typedef __attribute__((ext_vector_type(8))) short bf16x8;
typedef __attribute__((ext_vector_type(4))) float floatx4;

// RNE float->bf16 (finite inputs)
static __device__ __forceinline__ unsigned short f2bf(float f) {
  unsigned int u = __float_as_uint(f);
  unsigned int r = (u + 0x7fffu + ((u >> 16) & 1u)) >> 16;
  return (unsigned short)r;
}

// ---------------------------------------------------------------------------
// convert fp32 -> bf16, 8 elements/thread
// ---------------------------------------------------------------------------
__global__ __launch_bounds__(256) void convert_bf16_kernel(
    const float* __restrict__ in, unsigned short* __restrict__ out) {
  int g = blockIdx.x * 256 + threadIdx.x;
  const float4* p = (const float4*)in;
  float4 f0 = p[g * 2], f1 = p[g * 2 + 1];
  union { unsigned short u[8]; uint4 v; } pk;
  pk.u[0]=f2bf(f0.x); pk.u[1]=f2bf(f0.y); pk.u[2]=f2bf(f0.z); pk.u[3]=f2bf(f0.w);
  pk.u[4]=f2bf(f1.x); pk.u[5]=f2bf(f1.y); pk.u[6]=f2bf(f1.z); pk.u[7]=f2bf(f1.w);
  ((uint4*)out)[g] = pk.v;
}

// ---------------------------------------------------------------------------
// transpose + convert: W[R][Cn] fp32 -> Wt[Cn][R] bf16 (32x32 LDS tiles)
// ---------------------------------------------------------------------------
__global__ __launch_bounds__(256) void transpose_bf16_kernel(
    const float* __restrict__ W, unsigned short* __restrict__ Wt, int R, int Cn) {
  __shared__ unsigned short tile[32][33];
  const int c0 = blockIdx.x * 32, r0 = blockIdx.y * 32;
  const int tx = threadIdx.x & 31, ty = threadIdx.x >> 5;   // ty 0..7
#pragma unroll
  for (int i = 0; i < 4; ++i) {
    int r = ty + i * 8;
    tile[r][tx] = f2bf(W[(size_t)(r0 + r) * Cn + c0 + tx]);
  }
  __syncthreads();
#pragma unroll
  for (int i = 0; i < 4; ++i) {
    int r = ty + i * 8;
    Wt[(size_t)(c0 + r) * R + r0 + tx] = tile[tx][r];
  }
}

// ---------------------------------------------------------------------------
// bf16 MFMA GEMM (m97 structure): C[M,N] = A[M,K] @ Bt[N,K]^T + bias
// 128x128 tile, BK=32, 256 thr (4 waves, 2x2 quadrants of 64x64).
// ---------------------------------------------------------------------------
__global__ __launch_bounds__(256) void gemm_mfma_kernel(
    const unsigned short* __restrict__ A,   // [M,K] bf16
    const unsigned short* __restrict__ Bt,  // [N,K] bf16
    const float* __restrict__ bias,         // [N]
    float* __restrict__ C, int M, int N, int K) {
  __shared__ bf16x8 As[128 * 4];   // [row][32 bf16] row-major
  __shared__ bf16x8 Bs[128 * 4];
  const int tid  = threadIdx.x;
  const int wave = tid >> 6;
  const int lane = tid & 63;
  const int m0 = blockIdx.y * 128;
  const int n0 = blockIdx.x * 128;
  const int m_off = (wave >> 1) * 64;
  const int n_off = (wave & 1) * 64;
  const int lrow = lane >> 2;        // staging: 0..15
  const int lcol = (lane & 3) * 8;
  const int fr = lane & 15;          // fragment row/col
  const int fq = lane >> 4;          // 0..3

  floatx4 acc[4][4];
#pragma unroll
  for (int i = 0; i < 4; ++i)
#pragma unroll
    for (int j = 0; j < 4; ++j) acc[i][j] = (floatx4){0.f, 0.f, 0.f, 0.f};

  for (int k0 = 0; k0 < K; k0 += 32) {
#pragma unroll
    for (int s = 0; s < 2; ++s) {
      int q = wave * 2 + s;          // 0..7, 16 rows each
      const unsigned short* ga = A + (size_t)(m0 + q * 16 + lrow) * K + k0 + lcol;
      __builtin_amdgcn_global_load_lds(
          (const __attribute__((address_space(1))) void*)ga,
          (__attribute__((address_space(3))) void*)((char*)As + q * 1024), 16, 0, 0);
      const unsigned short* gb = Bt + (size_t)(n0 + q * 16 + lrow) * K + k0 + lcol;
      __builtin_amdgcn_global_load_lds(
          (const __attribute__((address_space(1))) void*)gb,
          (__attribute__((address_space(3))) void*)((char*)Bs + q * 1024), 16, 0, 0);
    }
    __syncthreads();
    bf16x8 a[4], b[4];
#pragma unroll
    for (int i = 0; i < 4; ++i) a[i] = As[(m_off + i * 16 + fr) * 4 + fq];
#pragma unroll
    for (int j = 0; j < 4; ++j) b[j] = Bs[(n_off + j * 16 + fr) * 4 + fq];
#pragma unroll
    for (int i = 0; i < 4; ++i)
#pragma unroll
      for (int j = 0; j < 4; ++j)
        acc[i][j] = __builtin_amdgcn_mfma_f32_16x16x32_bf16(a[i], b[j], acc[i][j], 0, 0, 0);
    __syncthreads();
  }
#pragma unroll
  for (int j = 0; j < 4; ++j) {
    int col = n0 + n_off + j * 16 + fr;
    float bv = bias[col];
#pragma unroll
    for (int i = 0; i < 4; ++i) {
#pragma unroll
      for (int r = 0; r < 4; ++r) {
        int row = m0 + m_off + i * 16 + fq * 4 + r;
        C[(size_t)row * N + col] = acc[i][j][r] + bv;
      }
    }
  }
}

// ---------------------------------------------------------------------------
// exact top-4 per tau row; registers + shuffle. Tie-break: lower index.
// ---------------------------------------------------------------------------
__global__ __launch_bounds__(256) void topk_kernel(
    const float* __restrict__ tau, int* __restrict__ idx_out) {
  const int row = blockIdx.x;
  const int tid = threadIdx.x;
  const float4* rp = (const float4*)(tau + (size_t)row * TT);
  float v[8];
  float4 f0 = rp[tid * 2], f1 = rp[tid * 2 + 1];
  v[0]=f0.x; v[1]=f0.y; v[2]=f0.z; v[3]=f0.w;
  v[4]=f1.x; v[5]=f1.y; v[6]=f1.z; v[7]=f1.w;
  __shared__ float wv[4];
  __shared__ int wi[4];
  __shared__ int winner;
  const int base = tid * 8;
  int chosen[KK];
  for (int r = 0; r < KK; ++r) {
    float bv = v[0]; int bi = base;
#pragma unroll
    for (int i = 1; i < 8; ++i)
      if (v[i] > bv) { bv = v[i]; bi = base + i; }   // strict > keeps lowest idx
#pragma unroll
    for (int off = 32; off > 0; off >>= 1) {
      float vv = __shfl_xor(bv, off, 64);
      int   ii = __shfl_xor(bi, off, 64);
      if (vv > bv || (vv == bv && ii < bi)) { bv = vv; bi = ii; }
    }
    if ((tid & 63) == 0) { wv[tid >> 6] = bv; wi[tid >> 6] = bi; }
    __syncthreads();
    if (tid == 0) {
      float b2 = wv[0]; int i2 = wi[0];
      for (int k = 1; k < 4; ++k)
        if (wv[k] > b2 || (wv[k] == b2 && wi[k] < i2)) { b2 = wv[k]; i2 = wi[k]; }
      winner = i2;
    }
    __syncthreads();
    int win = winner;
    chosen[r] = win;
    if ((win >> 3) == tid) v[win & 7] = -1e30f;
    __syncthreads();
  }
  if (tid < KK) idx_out[row * KK + tid] = chosen[tid];
}

// ---------------------------------------------------------------------------
// sparse attention at the 4 top-k keys; writes bf16 attn_out + sig.
// Block = one (b,t): 8 waves, wave h = head h, lane = d.
// ---------------------------------------------------------------------------
__global__ __launch_bounds__(512) void attn_kernel(
    const float* __restrict__ qkv, const float* __restrict__ tau,
    const int* __restrict__ idx_in, unsigned short* __restrict__ attn_bf,
    float* __restrict__ sig_out) {
  const int row  = blockIdx.x;          // b*T + t
  const int b    = row >> 11;
  const int tid  = threadIdx.x;
  const int h    = tid >> 6;
  const int lane = tid & 63;

  __shared__ int   idx4[KK];
  __shared__ float tau4[KK];
  __shared__ float ps[HH][KK];
  if (tid < KK) {
    int s = idx_in[row * KK + tid];
    idx4[tid] = s;
    tau4[tid] = tau[(size_t)row * TT + s];
  }
  __syncthreads();

  const float q = qkv[(size_t)row * C3 + h * DD + lane];
  int   sidx[KK];
  float logit[KK];
#pragma unroll
  for (int j = 0; j < KK; ++j) {
    sidx[j] = idx4[j];
    float kv = qkv[((size_t)(b * TT + sidx[j])) * C3 + CC + h * DD + lane];
    float p = q * kv;
#pragma unroll
    for (int off = 32; off > 0; off >>= 1) p += __shfl_xor(p, off, 64);
    logit[j] = p * 0.125f + 2.5f * logf(tau4[j] + 1e-8f);
  }

  float m = fmaxf(fmaxf(logit[0], logit[1]), fmaxf(logit[2], logit[3]));
  float p[KK], den = 0.f;
#pragma unroll
  for (int j = 0; j < KK; ++j) { p[j] = expf(logit[j] - m); den += p[j]; }
  float inv = 1.f / den;
#pragma unroll
  for (int j = 0; j < KK; ++j) p[j] *= inv;

  float o = 0.f;
#pragma unroll
  for (int j = 0; j < KK; ++j)
    o += p[j] * qkv[((size_t)(b * TT + sidx[j])) * C3 + 2 * CC + h * DD + lane];
  attn_bf[(size_t)row * CC + h * DD + lane] = f2bf(o);

  if (lane < KK) ps[h][lane] = p[lane];
  __syncthreads();
  if (tid < KK) {
    float s = 0.f;
#pragma unroll
    for (int k = 0; k < HH; ++k) s += ps[k][tid];
    sig_out[row * KK + tid] = s * (1.0f / HH);
  }
}

// ---------------------------------------------------------------------------
// tau EMA update + row-normalize + clip (float4, shuffle reduce)
// ---------------------------------------------------------------------------
__global__ __launch_bounds__(256) void tau_kernel(
    const float* __restrict__ tau, const int* __restrict__ idx_in,
    const float* __restrict__ sig_in, float* __restrict__ tau_out) {
  const int row = blockIdx.x;
  const int tid = threadIdx.x;
  int i4[KK]; float s3[KK];
#pragma unroll
  for (int j = 0; j < KK; ++j) {
    i4[j] = idx_in[row * KK + j];
    float s = sig_in[row * KK + j];
    s3[j] = s * s * s;
  }
  const float4* rp = (const float4*)(tau + (size_t)row * TT);
  float v[8];
  float4 f0 = rp[tid * 2], f1 = rp[tid * 2 + 1];
  v[0]=f0.x; v[1]=f0.y; v[2]=f0.z; v[3]=f0.w;
  v[4]=f1.x; v[5]=f1.y; v[6]=f1.z; v[7]=f1.w;
  const float keep = 1.0f - 0.085f;
  const int base = tid * 8;
  float local = 0.f;
#pragma unroll
  for (int i = 0; i < 8; ++i) {
    float t = keep * v[i];
#pragma unroll
    for (int j = 0; j < KK; ++j)
      if (base + i == i4[j]) t += s3[j];
    v[i] = t;
    local += t;
  }
#pragma unroll
  for (int off = 32; off > 0; off >>= 1) local += __shfl_xor(local, off, 64);
  __shared__ float wsum[4];
  __shared__ float tot;
  if ((tid & 63) == 0) wsum[tid >> 6] = local;
  __syncthreads();
  if (tid == 0) tot = wsum[0] + wsum[1] + wsum[2] + wsum[3];
  __syncthreads();
  float inv = 1.f / (tot + 1e-8f);
  float4* op = (float4*)(tau_out + (size_t)row * TT);
  float4 o0 = { fminf(v[0]*inv,5.f), fminf(v[1]*inv,5.f), fminf(v[2]*inv,5.f), fminf(v[3]*inv,5.f) };
  float4 o1 = { fminf(v[4]*inv,5.f), fminf(v[5]*inv,5.f), fminf(v[6]*inv,5.f), fminf(v[7]*inv,5.f) };
  op[tid * 2] = o0;
  op[tid * 2 + 1] = o1;
}

// ---------------------------------------------------------------------------
extern "C" void kernel_launch(void* const* d_in, const int* in_sizes, int n_in,
                              void* d_out, int out_size, void* d_ws, size_t ws_size,
                              hipStream_t stream) {
  const float* x     = (const float*)d_in[0];   // [B,T,C]
  const float* tau   = (const float*)d_in[1];   // [B,T,T]
  const float* Wqkv  = (const float*)d_in[2];   // [C,3C]
  const float* bqkv  = (const float*)d_in[3];   // [3C]
  const float* Wproj = (const float*)d_in[4];   // [C,C]
  const float* bproj = (const float*)d_in[5];   // [C]

  float* out     = (float*)d_out;               // [B,T,C]
  float* tau_new = out + (size_t)MROWS * CC;    // [B,T,T]

  char* w = (char*)d_ws;
  float* qkv = (float*)w;                w += (size_t)MROWS * C3 * 4;
  unsigned short* x_bf    = (unsigned short*)w; w += (size_t)MROWS * CC * 2;
  unsigned short* wqkv_t  = (unsigned short*)w; w += (size_t)C3 * CC * 2;
  unsigned short* wproj_t = (unsigned short*)w; w += (size_t)CC * CC * 2;
  unsigned short* attn_bf = (unsigned short*)w; w += (size_t)MROWS * CC * 2;
  int*   idx = (int*)w;                  w += (size_t)MROWS * KK * 4;
  float* sig = (float*)w;

  // converts
  convert_bf16_kernel<<<(MROWS * CC) / 2048, 256, 0, stream>>>(x, x_bf);
  transpose_bf16_kernel<<<dim3(C3 / 32, CC / 32), 256, 0, stream>>>(Wqkv, wqkv_t, CC, C3);
  transpose_bf16_kernel<<<dim3(CC / 32, CC / 32), 256, 0, stream>>>(Wproj, wproj_t, CC, CC);

  // top-4 indices of each tau row (independent of converts)
  topk_kernel<<<MROWS, 256, 0, stream>>>(tau, idx);

  // qkv = x @ Wqkv + bqkv   (MFMA)
  gemm_mfma_kernel<<<dim3(C3 / 128, MROWS / 128), 256, 0, stream>>>(
      x_bf, wqkv_t, bqkv, qkv, MROWS, C3, CC);

  // sparse attention + signal
  attn_kernel<<<MROWS, 512, 0, stream>>>(qkv, tau, idx, attn_bf, sig);

  // tau update
  tau_kernel<<<MROWS, 256, 0, stream>>>(tau, idx, sig, tau_new);

  // out = attn @ Wproj + bproj  (MFMA)
  gemm_mfma_kernel<<<dim3(CC / 128, MROWS / 128), 256, 0, stream>>>(
      attn_bf, wproj_t, bproj, out, MROWS, CC, CC);
}

// Round 3
// 150.580 us; speedup vs baseline: 1.9997x; 1.1568x over previous
//
#include <hip/hip_runtime.h>
#include <hip/hip_bf16.h>
#include <math.h>

// Shapes (fixed by the reference problem)
#define BB 2
#define TT 2048
#define CC 512
#define HH 8
#define DD 64
#define KK 4
#define C3 1536
#define MROWS (BB*TT)          // 4096

// GEMM tiling: 128(m) x 64(n), BK=32, 256 threads (4 waves of 64x32)
#define G1_NT (C3/64)          // 24
#define G1_BLOCKS (G1_NT*(MROWS/128))  // 768  -> 3 blocks/CU exact
#define G2_NT (CC/64)          // 8
#define G2_BLOCKS (G2_NT*(MROWS/128))  // 256  -> 1 block/CU exact

typedef __attribute__((ext_vector_type(8))) short bf16x8;
typedef __attribute__((ext_vector_type(4))) float floatx4;

static __device__ __forceinline__ unsigned short f2bf(float f) {
  unsigned int u = __float_as_uint(f);
  return (unsigned short)((u + 0x7fffu + ((u >> 16) & 1u)) >> 16);
}
static __device__ __forceinline__ float bf2f(unsigned short u) {
  return __uint_as_float(((unsigned int)u) << 16);
}

// ---------------------------------------------------------------------------
// GEMM body: C[M,N] = A[M,K] @ Bt[N,K]^T + bias. 128x64 tile, BK=32.
// BF16OUT selects bf16 vs fp32 output.
// ---------------------------------------------------------------------------
template<bool BF16OUT>
static __device__ __forceinline__ void gemm_body(
    int bid, int nt,
    const unsigned short* __restrict__ A,
    const unsigned short* __restrict__ Bt,
    const float* __restrict__ bias,
    void* __restrict__ Cout, int N, int K) {
  __shared__ bf16x8 As[128 * 4];   // [row][32 bf16]
  __shared__ bf16x8 Bs[64 * 4];
  const int tid  = threadIdx.x;
  const int wave = tid >> 6;
  const int lane = tid & 63;
  const int n0 = (bid % nt) * 64;
  const int m0 = (bid / nt) * 128;
  const int m_off = (wave >> 1) * 64;
  const int n_off = (wave & 1) * 32;
  const int lrow = lane >> 2;
  const int lcol = (lane & 3) * 8;
  const int fr = lane & 15;
  const int fq = lane >> 4;

  floatx4 acc[4][2];
#pragma unroll
  for (int i = 0; i < 4; ++i)
#pragma unroll
    for (int j = 0; j < 2; ++j) acc[i][j] = (floatx4){0.f, 0.f, 0.f, 0.f};

  for (int k0 = 0; k0 < K; k0 += 32) {
#pragma unroll
    for (int s = 0; s < 2; ++s) {
      int q = wave * 2 + s;          // 0..7 -> 128 A rows
      const unsigned short* ga = A + (size_t)(m0 + q * 16 + lrow) * K + k0 + lcol;
      __builtin_amdgcn_global_load_lds(
          (const __attribute__((address_space(1))) void*)ga,
          (__attribute__((address_space(3))) void*)((char*)As + q * 1024), 16, 0, 0);
    }
    const unsigned short* gb = Bt + (size_t)(n0 + wave * 16 + lrow) * K + k0 + lcol;
    __builtin_amdgcn_global_load_lds(
        (const __attribute__((address_space(1))) void*)gb,
        (__attribute__((address_space(3))) void*)((char*)Bs + wave * 1024), 16, 0, 0);
    __syncthreads();
    bf16x8 a[4], b[2];
#pragma unroll
    for (int i = 0; i < 4; ++i) a[i] = As[(m_off + i * 16 + fr) * 4 + fq];
#pragma unroll
    for (int j = 0; j < 2; ++j) b[j] = Bs[(n_off + j * 16 + fr) * 4 + fq];
#pragma unroll
    for (int i = 0; i < 4; ++i)
#pragma unroll
      for (int j = 0; j < 2; ++j)
        acc[i][j] = __builtin_amdgcn_mfma_f32_16x16x32_bf16(a[i], b[j], acc[i][j], 0, 0, 0);
    __syncthreads();
  }
#pragma unroll
  for (int j = 0; j < 2; ++j) {
    int col = n0 + n_off + j * 16 + fr;
    float bv = bias[col];
#pragma unroll
    for (int i = 0; i < 4; ++i) {
#pragma unroll
      for (int r = 0; r < 4; ++r) {
        int row = m0 + m_off + i * 16 + fq * 4 + r;
        float v = acc[i][j][r] + bv;
        if (BF16OUT) ((unsigned short*)Cout)[(size_t)row * N + col] = f2bf(v);
        else         ((float*)Cout)[(size_t)row * N + col] = v;
      }
    }
  }
}

// ---------------------------------------------------------------------------
// top-4 body: exact, tie-break lower index (matches jax.lax.top_k)
// ---------------------------------------------------------------------------
static __device__ __forceinline__ void topk_body(
    int row, const float* __restrict__ tau, int* __restrict__ idx_out) {
  const int tid = threadIdx.x;
  const float4* rp = (const float4*)(tau + (size_t)row * TT);
  float v[8];
  float4 f0 = rp[tid * 2], f1 = rp[tid * 2 + 1];
  v[0]=f0.x; v[1]=f0.y; v[2]=f0.z; v[3]=f0.w;
  v[4]=f1.x; v[5]=f1.y; v[6]=f1.z; v[7]=f1.w;
  __shared__ float wv[4];
  __shared__ int wi[4];
  __shared__ int winner;
  const int base = tid * 8;
  int chosen[KK];
  for (int r = 0; r < KK; ++r) {
    float bv = v[0]; int bi = base;
#pragma unroll
    for (int i = 1; i < 8; ++i)
      if (v[i] > bv) { bv = v[i]; bi = base + i; }
#pragma unroll
    for (int off = 32; off > 0; off >>= 1) {
      float vv = __shfl_xor(bv, off, 64);
      int   ii = __shfl_xor(bi, off, 64);
      if (vv > bv || (vv == bv && ii < bi)) { bv = vv; bi = ii; }
    }
    if ((tid & 63) == 0) { wv[tid >> 6] = bv; wi[tid >> 6] = bi; }
    __syncthreads();
    if (tid == 0) {
      float b2 = wv[0]; int i2 = wi[0];
      for (int k = 1; k < 4; ++k)
        if (wv[k] > b2 || (wv[k] == b2 && wi[k] < i2)) { b2 = wv[k]; i2 = wi[k]; }
      winner = i2;
    }
    __syncthreads();
    int win = winner;
    chosen[r] = win;
    if ((win >> 3) == tid) v[win & 7] = -1e30f;
    __syncthreads();
  }
  if (tid < KK) idx_out[row * KK + tid] = chosen[tid];
}

// ---------------------------------------------------------------------------
// tau EMA + normalize + clip body
// ---------------------------------------------------------------------------
static __device__ __forceinline__ void tau_body(
    int row, const float* __restrict__ tau, const int* __restrict__ idx_in,
    const float* __restrict__ sig_in, float* __restrict__ tau_out) {
  const int tid = threadIdx.x;
  int i4[KK]; float s3[KK];
#pragma unroll
  for (int j = 0; j < KK; ++j) {
    i4[j] = idx_in[row * KK + j];
    float s = sig_in[row * KK + j];
    s3[j] = s * s * s;
  }
  const float4* rp = (const float4*)(tau + (size_t)row * TT);
  float v[8];
  float4 f0 = rp[tid * 2], f1 = rp[tid * 2 + 1];
  v[0]=f0.x; v[1]=f0.y; v[2]=f0.z; v[3]=f0.w;
  v[4]=f1.x; v[5]=f1.y; v[6]=f1.z; v[7]=f1.w;
  const float keep = 1.0f - 0.085f;
  const int base = tid * 8;
  float local = 0.f;
#pragma unroll
  for (int i = 0; i < 8; ++i) {
    float t = keep * v[i];
#pragma unroll
    for (int j = 0; j < KK; ++j)
      if (base + i == i4[j]) t += s3[j];
    v[i] = t;
    local += t;
  }
#pragma unroll
  for (int off = 32; off > 0; off >>= 1) local += __shfl_xor(local, off, 64);
  __shared__ float wsum[4];
  __shared__ float tot;
  if ((tid & 63) == 0) wsum[tid >> 6] = local;
  __syncthreads();
  if (tid == 0) tot = wsum[0] + wsum[1] + wsum[2] + wsum[3];
  __syncthreads();
  float inv = 1.f / (tot + 1e-8f);
  float4* op = (float4*)(tau_out + (size_t)row * TT);
  float4 o0 = { fminf(v[0]*inv,5.f), fminf(v[1]*inv,5.f), fminf(v[2]*inv,5.f), fminf(v[3]*inv,5.f) };
  float4 o1 = { fminf(v[4]*inv,5.f), fminf(v[5]*inv,5.f), fminf(v[6]*inv,5.f), fminf(v[7]*inv,5.f) };
  op[tid * 2] = o0;
  op[tid * 2 + 1] = o1;
}

// ---------------------------------------------------------------------------
// transpose+convert body: W[R][Cn] fp32 -> Wt[Cn][R] bf16, 32x32 tiles
// ---------------------------------------------------------------------------
static __device__ __forceinline__ void transpose_body(
    int t, int nbx, const float* __restrict__ W, unsigned short* __restrict__ Wt,
    int R, int Cn) {
  __shared__ unsigned short tile[32][33];
  const int c0 = (t % nbx) * 32, r0 = (t / nbx) * 32;
  const int tx = threadIdx.x & 31, ty = threadIdx.x >> 5;
#pragma unroll
  for (int i = 0; i < 4; ++i) {
    int r = ty + i * 8;
    tile[r][tx] = f2bf(W[(size_t)(r0 + r) * Cn + c0 + tx]);
  }
  __syncthreads();
#pragma unroll
  for (int i = 0; i < 4; ++i) {
    int r = ty + i * 8;
    Wt[(size_t)(c0 + r) * R + r0 + tx] = tile[tx][r];
  }
}

// ---------------------------------------------------------------------------
// Kernel 1: all input conversions (x->bf16, Wqkv^T, Wproj^T)
// ---------------------------------------------------------------------------
__global__ __launch_bounds__(256) void prep_kernel(
    const float* __restrict__ x, unsigned short* __restrict__ x_bf,
    const float* __restrict__ Wqkv, unsigned short* __restrict__ wqkv_t,
    const float* __restrict__ Wproj, unsigned short* __restrict__ wproj_t) {
  const int bid = blockIdx.x;
  if (bid < 1024) {                       // convert x: 2M elements, 8/thread
    int g = bid * 256 + threadIdx.x;
    const float4* p = (const float4*)x;
    float4 f0 = p[g * 2], f1 = p[g * 2 + 1];
    union { unsigned short u[8]; uint4 v; } pk;
    pk.u[0]=f2bf(f0.x); pk.u[1]=f2bf(f0.y); pk.u[2]=f2bf(f0.z); pk.u[3]=f2bf(f0.w);
    pk.u[4]=f2bf(f1.x); pk.u[5]=f2bf(f1.y); pk.u[6]=f2bf(f1.z); pk.u[7]=f2bf(f1.w);
    ((uint4*)x_bf)[g] = pk.v;
  } else if (bid < 1024 + 768) {          // Wqkv [512,1536] -> [1536,512]
    transpose_body(bid - 1024, C3 / 32, Wqkv, wqkv_t, CC, C3);
  } else {                                // Wproj [512,512] -> [512,512]^T
    transpose_body(bid - 1792, CC / 32, Wproj, wproj_t, CC, CC);
  }
}

// ---------------------------------------------------------------------------
// Kernel 2: GEMM1 (qkv, bf16 out) blocks [0,768) + topk blocks [768,768+4096)
// ---------------------------------------------------------------------------
__global__ __launch_bounds__(256) void gemm1_topk_kernel(
    const unsigned short* __restrict__ x_bf,
    const unsigned short* __restrict__ wqkv_t,
    const float* __restrict__ bqkv, unsigned short* __restrict__ qkv_bf,
    const float* __restrict__ tau, int* __restrict__ idx_out) {
  if (blockIdx.x < G1_BLOCKS)
    gemm_body<true>(blockIdx.x, G1_NT, x_bf, wqkv_t, bqkv, qkv_bf, C3, CC);
  else
    topk_body(blockIdx.x - G1_BLOCKS, tau, idx_out);
}

// ---------------------------------------------------------------------------
// Kernel 3: sparse attention at the 4 top-k keys (bf16 qkv in, bf16 out)
// ---------------------------------------------------------------------------
__global__ __launch_bounds__(512) void attn_kernel(
    const unsigned short* __restrict__ qkv, const float* __restrict__ tau,
    const int* __restrict__ idx_in, unsigned short* __restrict__ attn_bf,
    float* __restrict__ sig_out) {
  const int row  = blockIdx.x;          // b*T + t
  const int b    = row >> 11;
  const int tid  = threadIdx.x;
  const int h    = tid >> 6;
  const int lane = tid & 63;

  __shared__ int   idx4[KK];
  __shared__ float tau4[KK];
  __shared__ float ps[HH][KK];
  if (tid < KK) {
    int s = idx_in[row * KK + tid];
    idx4[tid] = s;
    tau4[tid] = tau[(size_t)row * TT + s];
  }
  __syncthreads();

  const float q = bf2f(qkv[(size_t)row * C3 + h * DD + lane]);
  int   sidx[KK];
  float logit[KK];
#pragma unroll
  for (int j = 0; j < KK; ++j) {
    sidx[j] = idx4[j];
    float kv = bf2f(qkv[((size_t)(b * TT + sidx[j])) * C3 + CC + h * DD + lane]);
    float p = q * kv;
#pragma unroll
    for (int off = 32; off > 0; off >>= 1) p += __shfl_xor(p, off, 64);
    logit[j] = p * 0.125f + 2.5f * logf(tau4[j] + 1e-8f);
  }

  float m = fmaxf(fmaxf(logit[0], logit[1]), fmaxf(logit[2], logit[3]));
  float p[KK], den = 0.f;
#pragma unroll
  for (int j = 0; j < KK; ++j) { p[j] = expf(logit[j] - m); den += p[j]; }
  float inv = 1.f / den;
#pragma unroll
  for (int j = 0; j < KK; ++j) p[j] *= inv;

  float o = 0.f;
#pragma unroll
  for (int j = 0; j < KK; ++j)
    o += p[j] * bf2f(qkv[((size_t)(b * TT + sidx[j])) * C3 + 2 * CC + h * DD + lane]);
  attn_bf[(size_t)row * CC + h * DD + lane] = f2bf(o);

  if (lane < KK) ps[h][lane] = p[lane];
  __syncthreads();
  if (tid < KK) {
    float s = 0.f;
#pragma unroll
    for (int k = 0; k < HH; ++k) s += ps[k][tid];
    sig_out[row * KK + tid] = s * (1.0f / HH);
  }
}

// ---------------------------------------------------------------------------
// Kernel 4: GEMM2 (out, fp32) blocks [0,256) + tau update blocks [256,256+4096)
// ---------------------------------------------------------------------------
__global__ __launch_bounds__(256) void gemm2_tau_kernel(
    const unsigned short* __restrict__ attn_bf,
    const unsigned short* __restrict__ wproj_t,
    const float* __restrict__ bproj, float* __restrict__ out,
    const float* __restrict__ tau, const int* __restrict__ idx_in,
    const float* __restrict__ sig_in, float* __restrict__ tau_out) {
  if (blockIdx.x < G2_BLOCKS)
    gemm_body<false>(blockIdx.x, G2_NT, attn_bf, wproj_t, bproj, out, CC, CC);
  else
    tau_body(blockIdx.x - G2_BLOCKS, tau, idx_in, sig_in, tau_out);
}

// ---------------------------------------------------------------------------
extern "C" void kernel_launch(void* const* d_in, const int* in_sizes, int n_in,
                              void* d_out, int out_size, void* d_ws, size_t ws_size,
                              hipStream_t stream) {
  const float* x     = (const float*)d_in[0];   // [B,T,C]
  const float* tau   = (const float*)d_in[1];   // [B,T,T]
  const float* Wqkv  = (const float*)d_in[2];   // [C,3C]
  const float* bqkv  = (const float*)d_in[3];   // [3C]
  const float* Wproj = (const float*)d_in[4];   // [C,C]
  const float* bproj = (const float*)d_in[5];   // [C]

  float* out     = (float*)d_out;               // [B,T,C]
  float* tau_new = out + (size_t)MROWS * CC;    // [B,T,T]

  char* w = (char*)d_ws;
  unsigned short* qkv_bf  = (unsigned short*)w; w += (size_t)MROWS * C3 * 2;
  unsigned short* x_bf    = (unsigned short*)w; w += (size_t)MROWS * CC * 2;
  unsigned short* wqkv_t  = (unsigned short*)w; w += (size_t)C3 * CC * 2;
  unsigned short* wproj_t = (unsigned short*)w; w += (size_t)CC * CC * 2;
  unsigned short* attn_bf = (unsigned short*)w; w += (size_t)MROWS * CC * 2;
  int*   idx = (int*)w;                  w += (size_t)MROWS * KK * 4;
  float* sig = (float*)w;

  // 1) converts: x->bf16, Wqkv^T, Wproj^T
  prep_kernel<<<2048, 256, 0, stream>>>(x, x_bf, Wqkv, wqkv_t, Wproj, wproj_t);

  // 2) qkv GEMM (bf16 out) + top-4 of tau rows, one kernel
  gemm1_topk_kernel<<<G1_BLOCKS + MROWS, 256, 0, stream>>>(
      x_bf, wqkv_t, bqkv, qkv_bf, tau, idx);

  // 3) sparse attention + signal
  attn_kernel<<<MROWS, 512, 0, stream>>>(qkv_bf, tau, idx, attn_bf, sig);

  // 4) out GEMM (fp32) + tau update, one kernel
  gemm2_tau_kernel<<<G2_BLOCKS + MROWS, 256, 0, stream>>>(
      attn_bf, wproj_t, bproj, out, tau, idx, sig, tau_new);
}